// Round 7
// baseline (375.124 us; speedup 1.0000x reference)
//
#include <hip/hip_runtime.h>
#include <hip/hip_bf16.h>
#include <math.h>

#define NN 4096
#define DD 256
#define TWO_N 8192
#define SCALE 14.426950408889634f   // (1/T)*log2(e)
#define INV_2N (1.0f/8192.0f)

typedef __bf16 bf16_t;
typedef bf16_t bf16x8 __attribute__((ext_vector_type(8)));
typedef bf16_t bf16x4 __attribute__((ext_vector_type(4)));
typedef float f32x4 __attribute__((ext_vector_type(4)));

// ---------------- normalize rows -> bf16 Zn ; zero possum/out ----------------
__global__ __launch_bounds__(256) void knorm(const float* __restrict__ zi,
                                             const float* __restrict__ zj,
                                             bf16_t* __restrict__ zn,
                                             float* __restrict__ possum,
                                             float* __restrict__ out) {
    const int wid = threadIdx.x >> 6, lane = threadIdx.x & 63;
    const int b = blockIdx.x;
    if (b == 0 && threadIdx.x == 0) { possum[0] = 0.0f; out[0] = 0.0f; }
    const int row = b * 4 + wid;                   // grid = 2048 -> rows 0..8191
    const float* src = (row < NN) ? (zi + (size_t)row * DD)
                                  : (zj + (size_t)(row - NN) * DD);
    float4 v = *(const float4*)(src + lane * 4);
    float ss = v.x*v.x + v.y*v.y + v.z*v.z + v.w*v.w;
    #pragma unroll
    for (int m = 1; m < 64; m <<= 1) ss += __shfl_xor(ss, m);
    const float sc = 1.0f / fmaxf(sqrtf(ss), 1e-8f);
    bf16x4 o;
    o[0] = (bf16_t)(v.x * sc);
    o[1] = (bf16_t)(v.y * sc);
    o[2] = (bf16_t)(v.z * sc);
    o[3] = (bf16_t)(v.w * sc);
    *(bf16x4*)(zn + (size_t)row * DD + lane * 4) = o;
}

// ---------------- main: upper-triangular 256x256 tiles of exp(sim/T) ----------------
// grid = 528 (= 32*33/2) blocks, 512 threads = 8 waves (2 x 4), wave tile 128x64.
// K = 256 in 8 chunks of 32, double-buffered LDS (64 KB), counted vmcnt.
// XCD-arc swizzle: 528 = 8*66 -> each XCD gets a contiguous triangular arc.
__global__ __launch_bounds__(512, 2) void kmain(const bf16_t* __restrict__ zn,
                                                float* __restrict__ PR,
                                                float* __restrict__ PC,
                                                float* __restrict__ possum) {
    __shared__ char ldsA[2][16384];   // [256 rows][32 bf16 = 64 B], XOR-swizzled
    __shared__ char ldsB[2][16384];
    const int tid = threadIdx.x, wid = tid >> 6, lane = tid & 63;

    const int bid = (int)blockIdx.x;
    const int wg  = (bid & 7) * 66 + (bid >> 3);   // bijective XCD arc swizzle

    // triangular decode over 32 tile-rows
    int ti = 0, rem = wg;
    while (rem >= 32 - ti) { rem -= 32 - ti; ++ti; }
    const int tj = ti + rem;
    const int rowbase = ti << 8, colbase = tj << 8;
    const int tile = ti * 32 + tj;

    const int wr = wid >> 2, wc = wid & 3;         // 2x4 wave grid; wave = 128x64
    const int lo = lane & 15, hi = lane >> 4;

    f32x4 acc[8][4];
    #pragma unroll
    for (int s = 0; s < 8; ++s)
        #pragma unroll
        for (int t = 0; t < 4; ++t) acc[s][t] = (f32x4){0, 0, 0, 0};

    const char* gz = (const char*)zn;              // zn rows are 512 bytes

    // stage A+B 256x32 chunks (16 KB each) for K-chunk q into buffer buf.
    // Linear LDS dest (wave-uniform base + lane*16); inverse-XOR-swizzled
    // global source: col ^ ((row&3)<<4) within the 64-byte row.
    auto stage = [&](int buf, int q) {
        #pragma unroll
        for (int p = 0; p < 2; ++p) {
            const int base = p * 8192 + wid * 1024;          // wave-uniform
            const int dd   = base + lane * 16;               // what HW writes
            const int row  = dd >> 6, col = dd & 63;
            const int scol = col ^ ((row & 3) << 4);
            const char* ga = gz + (size_t)(rowbase + row) * 512 + q * 64 + scol;
            const char* gb = gz + (size_t)(colbase + row) * 512 + q * 64 + scol;
            __builtin_amdgcn_global_load_lds(
                (const __attribute__((address_space(1))) void*)ga,
                (__attribute__((address_space(3))) void*)(&ldsA[buf][base]), 16, 0, 0);
            __builtin_amdgcn_global_load_lds(
                (const __attribute__((address_space(1))) void*)gb,
                (__attribute__((address_space(3))) void*)(&ldsB[buf][base]), 16, 0, 0);
        }
    };

    // per-lane swizzled LDS read bases (row&3 == lo&3 since strides are mult of 4)
    const int aoff = (wr * 128 + lo) * 64 + ((hi * 16) ^ ((lo & 3) << 4));
    const int boff = (wc * 64 + lo) * 64 + ((hi * 16) ^ ((lo & 3) << 4));

    stage(0, 0);                                   // prologue

    for (int q = 0; q < 8; ++q) {
        const int cur = q & 1;
        if (q < 7) {
            stage(cur ^ 1, q + 1);                 // prefetch next chunk
            asm volatile("s_waitcnt vmcnt(4)" ::: "memory");  // cur's 4 loads done
        } else {
            asm volatile("s_waitcnt vmcnt(0)" ::: "memory");
        }
        __builtin_amdgcn_s_barrier();
        __builtin_amdgcn_sched_barrier(0);

        bf16x8 af[8], bf[4];
        #pragma unroll
        for (int s = 0; s < 8; ++s)
            af[s] = *(const bf16x8*)(&ldsA[cur][aoff + s * 1024]);
        #pragma unroll
        for (int t = 0; t < 4; ++t)
            bf[t] = *(const bf16x8*)(&ldsB[cur][boff + t * 1024]);

        #pragma unroll
        for (int s = 0; s < 8; ++s)
            #pragma unroll
            for (int t = 0; t < 4; ++t)
                acc[s][t] = __builtin_amdgcn_mfma_f32_16x16x32_bf16(
                    af[s], bf[t], acc[s][t], 0, 0, 0);

        if (q < 7) __builtin_amdgcn_s_barrier();   // all reads of cur done
    }

    // ---- positives: tiles with tj == ti+16 (global col = row + 4096) ----
    // diag element local (d,d): wave covers it iff (wc>>1)==wr; acc s-index
    // = (wc&1)*4 + t, with per-lane j = lo - hi*4 in [0,4).
    if (tj == ti + 16 && (wc >> 1) == wr) {
        const int j = lo - hi * 4;
        float p = 0.0f;
        if (j >= 0 && j < 4) {
            #pragma unroll
            for (int t = 0; t < 4; ++t) p += acc[(wc & 1) * 4 + t][t][j];
        }
        #pragma unroll
        for (int m = 1; m < 64; m <<= 1) p += __shfl_xor(p, m);
        if (lane == 0) atomicAdd(possum, p);
    }

    // ---- snap self-similarity diagonal to exactly 1.0 ----
    if (ti == tj && (wc >> 1) == wr) {
        const int j = lo - hi * 4;
        if (j >= 0 && j < 4) {
            #pragma unroll
            for (int t = 0; t < 4; ++t) acc[(wc & 1) * 4 + t][t][j] = 1.0f;
        }
    }

    // ---- exp in place ----
    #pragma unroll
    for (int s = 0; s < 8; ++s)
        #pragma unroll
        for (int t = 0; t < 4; ++t)
            #pragma unroll
            for (int j = 0; j < 4; ++j)
                acc[s][t][j] = __builtin_amdgcn_exp2f(acc[s][t][j] * SCALE);

    // ---- row partial sums -> PR[tile][wc][row 0..255] (plain stores) ----
    {
        float* PRb = PR + (((size_t)tile * 4 + wc) << 8) + wr * 128;
        #pragma unroll
        for (int s = 0; s < 8; ++s) {
            f32x4 rs = acc[s][0] + acc[s][1] + acc[s][2] + acc[s][3];
            #pragma unroll
            for (int j = 0; j < 4; ++j) {
                float v = rs[j];
                v += __shfl_xor(v, 1); v += __shfl_xor(v, 2);
                v += __shfl_xor(v, 4); v += __shfl_xor(v, 8);
                if (lo == 0) PRb[s * 16 + hi * 4 + j] = v;
            }
        }
    }

    // ---- col partial sums -> PC[tile][wr][col 0..255] (off-diagonal only) ----
    if (ti != tj) {
        float* PCb = PC + (((size_t)tile * 2 + wr) << 8) + wc * 64;
        #pragma unroll
        for (int t = 0; t < 4; ++t) {
            float v = 0.0f;
            #pragma unroll
            for (int s = 0; s < 8; ++s)
                v += acc[s][t][0] + acc[s][t][1] + acc[s][t][2] + acc[s][t][3];
            v += __shfl_xor(v, 16); v += __shfl_xor(v, 32);
            if (hi == 0) PCb[t * 16 + lo] = v;
        }
    }
}

// ---------------- final: gather partials, logs, scalar reduction ----------------
// grid = 32 blocks (one per tile-row a) x 256 threads (one per row in tile).
// Reads ONLY written slots: PR[a][t>=a][0..3][rr], PC[b<a][a][0..1][rr].
__global__ __launch_bounds__(256) void kfinal(const float* __restrict__ PR,
                                              const float* __restrict__ PC,
                                              const float* __restrict__ possum,
                                              float* __restrict__ out) {
    __shared__ float red[4];
    const int a = blockIdx.x;
    const int rr = threadIdx.x;                    // 0..255
    const int wid = threadIdx.x >> 6, lane = threadIdx.x & 63;
    float total = 0.0f;
    for (int t = a; t < 32; ++t) {
        const size_t tb = ((size_t)(a * 32 + t) * 4) << 8;
        total += PR[tb + rr] + PR[tb + 256 + rr] + PR[tb + 512 + rr] + PR[tb + 768 + rr];
    }
    for (int b = 0; b < a; ++b) {
        const size_t tb = ((size_t)(b * 32 + a) * 2) << 8;
        total += PC[tb + rr] + PC[tb + 256 + rr];
    }
    float v = logf(total * INV_2N);
    #pragma unroll
    for (int m = 1; m < 64; m <<= 1) v += __shfl_xor(v, m);
    if (lane == 0) red[wid] = v;
    __syncthreads();
    if (threadIdx.x == 0) {
        float s = red[0] + red[1] + red[2] + red[3];
        if (a == 0) s -= 20.0f * possum[0];        // (1/T)*sum(pos), pos counted twice
        atomicAdd(out, s * INV_2N);
    }
}

extern "C" void kernel_launch(void* const* d_in, const int* in_sizes, int n_in,
                              void* d_out, int out_size, void* d_ws, size_t ws_size,
                              hipStream_t stream) {
    const float* zi = (const float*)d_in[0];
    const float* zj = (const float*)d_in[1];
    bf16_t* zn     = (bf16_t*)d_ws;                                  // [0, 4MB)
    float*  PR     = (float*)((char*)d_ws + ((size_t)4 << 20));      // [4MB, 8MB)  32*32*4*256*4B = 4MB
    float*  PC     = (float*)((char*)d_ws + ((size_t)8 << 20));      // [8MB, 10MB) 32*32*2*256*4B = 2MB
    float*  possum = (float*)((char*)d_ws + ((size_t)10 << 20));
    float*  out    = (float*)d_out;

    knorm <<<2048, 256, 0, stream>>>(zi, zj, zn, possum, out);
    kmain <<<528,  512, 0, stream>>>(zn, PR, PC, possum);
    kfinal<<<32,   256, 0, stream>>>(PR, PC, possum, out);
}